// Round 1
// baseline (938.208 us; speedup 1.0000x reference)
//
#include <hip/hip_runtime.h>

// Problem constants
#define NA 32   // atoms A
#define NB 2    // batch B
#define NC 16   // channels C

// ---- coupling tables (l-grouped, loop order of the reference) ----
// l=0: (0,0,0),(1,1,0),(2,2,0)
// l=1: (0,1,1),(1,0,1),(1,1,1),(1,2,1),(2,1,1),(2,2,1)
// l=2: (0,2,2),(1,1,2),(1,2,2),(2,0,2),(2,1,2),(2,2,2)
__constant__ int CP_L1[15]   = {0,1,2, 0,1,1,1,2,2, 0,1,1,2,2,2};
__constant__ int CP_L2[15]   = {0,1,2, 1,0,1,2,1,2, 2,1,2,0,1,2};
__constant__ int CP_LOUT[15] = {0,0,0, 1,1,1,1,1,1, 2,2,2,2,2,2};
__constant__ int CP_OFF[15]  = {0,1,10, 35,44,53,80,125,170, 245,270,315,390,415,490};
__constant__ int LBASE[3] = {0,3,9};      // first coupling index per output l
__constant__ int LOFF[3]  = {0,1,4};      // x_total offset per l (m-dims 1,3,5)
__constant__ int OFF3[3]  = {0,1024,4096};// per-l float offset inside a parts/mnl buffer (sizes 1024,3072,5120)

// ---------------- CG coefficient setup (device, every call) ----------------
__device__ double dfact(int n) { double r = 1.0; for (int i = 2; i <= n; ++i) r *= (double)i; return r; }

__global__ void k_cg(float* __restrict__ cg)
{
    for (int cp = 0; cp < 15; ++cp) {
        int l1 = CP_L1[cp], l2 = CP_L2[cp], l = CP_LOUT[cp];
        int n1 = 2*l1+1, n2 = 2*l2+1, nl = 2*l+1;
        int n = n1 * n2 * nl;
        for (int e = threadIdx.x; e < n; e += blockDim.x) {
            int z = e % nl;
            int y = (e / nl) % n2;
            int x = e / (nl * n2);
            int m1 = x - l1, m2 = y - l2, m = z - l;
            float val = 0.0f;
            if (m1 + m2 == m) {
                double pre = sqrt((2.0*l+1.0) * dfact(l+l1-l2) * dfact(l-l1+l2) * dfact(l1+l2-l) / dfact(l1+l2+l+1));
                pre *= sqrt(dfact(l+m)*dfact(l-m)*dfact(l1+m1)*dfact(l1-m1)*dfact(l2+m2)*dfact(l2-m2));
                double s = 0.0;
                for (int k = 0; k <= l1+l2; ++k) {
                    int d0=k, d1=l1+l2-l-k, d2=l1-m1-k, d3=l2+m2-k, d4=l-l2+m1+k, d5=l-l1-m2+k;
                    if (d0<0||d1<0||d2<0||d3<0||d4<0||d5<0) continue;
                    s += ((k & 1) ? -1.0 : 1.0) / (dfact(d0)*dfact(d1)*dfact(d2)*dfact(d3)*dfact(d4)*dfact(d5));
                }
                val = (float)(pre * s);
            }
            cg[CP_OFF[cp] + e] = val;
        }
    }
}

// ---------------- K1: message pass + cg_nl + wnl mixing ----------------
// one block per atom i; template L = output l
template<int L>
__global__ __launch_bounds__(256) void k_nl(
    const float* __restrict__ p0, const float* __restrict__ p1, const float* __restrict__ p2,
    const float* __restrict__ norms, const float* __restrict__ wnl,
    const float* __restrict__ cg, float* __restrict__ mnl)
{
    constexpr int MD  = 2*L+1;
    constexpr int TAU = (L == 0) ? 768 : 1536;
    constexpr int NBZ = NB * MD;

    __shared__ float shmp[NB*9*NC];          // mp[b][x_total][c]
    __shared__ float shcg[NB*MD*TAU];        // cg_nl[(b*MD+z)*TAU + t]
    __shared__ float shred[4*16*NBZ];

    const int i = blockIdx.x;
    const int tid = threadIdx.x;

    // mp[b, lp, x, c] = sum_j conn(b,i,j) * parts[lp][b,j,x,c]
    for (int e = tid; e < NB*9*NC; e += 256) {
        int b = e / (9*NC); int rem = e % (9*NC);
        int xt = rem / NC;  int c = rem % NC;
        int lp = (xt < 1) ? 0 : ((xt < 4) ? 1 : 2);
        int x = xt - LOFF[lp];
        int md = 2*lp+1;
        const float* pp = (lp == 0) ? p0 : ((lp == 1) ? p1 : p2);
        const float* nr = norms + (b*NA + i)*NA;
        float s = 0.0f;
        for (int j = 0; j < NA; ++j) {
            if (nr[j] < 0.5f) s += pp[((b*NA + j)*md + x)*NC + c];
        }
        shmp[e] = s;
    }
    __syncthreads();

    // cg_nl[b,z,t], t = k*256 + c*16 + d
    for (int e = tid; e < NB*MD*TAU; e += 256) {
        int t = e % TAU; int rem = e / TAU;
        int z = rem % MD; int b = rem / MD;
        int k = t >> 8; int c = (t >> 4) & 15; int d = t & 15;
        int cp = LBASE[L] + k;
        int l1 = CP_L1[cp], l2 = CP_L2[cp];
        int n1 = 2*l1+1, n2 = 2*l2+1;
        const float* cgp = cg + CP_OFF[cp];
        float s = 0.0f;
        for (int x = 0; x < n1; ++x) {
            float mv = shmp[(b*9 + LOFF[l1] + x)*NC + c];
            for (int y = 0; y < n2; ++y)
                s += cgp[(x*n2 + y)*MD + z] * mv * shmp[(b*9 + LOFF[l2] + y)*NC + d];
        }
        shcg[e] = s;
    }
    __syncthreads();

    // mixed_nl[b,z,c'] = sum_t cg_nl[b,z,t] * wnl[i,t,c']
    const int cidx = tid & 15, tg = tid >> 4;
    float acc[NBZ];
#pragma unroll
    for (int q = 0; q < NBZ; ++q) acc[q] = 0.0f;
    for (int s = 0; s < TAU/16; ++s) {
        int t = tg + (s << 4);
        float wv = wnl[(i*TAU + t)*NC + cidx];
#pragma unroll
        for (int q = 0; q < NBZ; ++q) acc[q] += shcg[q*TAU + t] * wv;
    }
#pragma unroll
    for (int q = 0; q < NBZ; ++q) {
        float v = acc[q];
        v += __shfl_xor(v, 16);
        v += __shfl_xor(v, 32);
        acc[q] = v;
    }
    const int wave = tid >> 6, lane = tid & 63;
    if (lane < 16) {
#pragma unroll
        for (int q = 0; q < NBZ; ++q) shred[(wave*16 + lane)*NBZ + q] = acc[q];
    }
    __syncthreads();
    for (int e = tid; e < 16*NBZ; e += 256) {
        int cc = e & 15, q = e >> 4;
        float s = 0.0f;
        for (int w = 0; w < 4; ++w) s += shred[(w*16 + cc)*NBZ + q];
        int b = q / MD, z = q % MD;
        mnl[OFF3[L] + ((b*NA + i)*MD + z)*NC + cc] = s;
    }
}

// ---------------- K2: rel CG product + wrel contraction + j-sum ----------------
template<int NBZ, int TPR>
__device__ inline void stream_part(const float* __restrict__ wb, const float* __restrict__ shG,
                                   float4* acc, int tid, int wave)
{
    for (int rq = 0; rq < TPR/4; ++rq) {
        const float4 v = *reinterpret_cast<const float4*>(wb + rq*1024 + tid*4);
        int r = rq*4 + wave;
#pragma unroll
        for (int q = 0; q < NBZ; ++q) {
            float g = shG[q*TPR + r];
            acc[q].x += g*v.x; acc[q].y += g*v.y; acc[q].z += g*v.z; acc[q].w += g*v.w;
        }
    }
}

__global__ __launch_bounds__(256) void k_rel(
    const float* __restrict__ mnl, const float* __restrict__ relpos,
    const float* __restrict__ wr0, const float* __restrict__ wr1, const float* __restrict__ wr2,
    const float* __restrict__ cg, float* __restrict__ pout)
{
    __shared__ float  shY[NB*9];
    __shared__ float  shM[NB*9*NC];
    __shared__ float  shG[1632];          // l0:96 @0, l1:576 @96, l2:960 @672
    __shared__ float4 shR[16*18];

    const int bx = blockIdx.x;
    const int i = bx >> 5, j = bx & 31;
    const int tid = threadIdx.x;

    if (tid < NB) {
        int b = tid;
        const float* rp = relpos + (((size_t)(b*NA + i))*NA + j)*3;
        float px = rp[0], py = rp[1], pz = rp[2];
        float r = sqrtf(px*px + py*py + pz*pz + 1e-6f);
        float ux = px/r, uy = py/r, uz = pz/r;
        shY[b*9+0] = 0.28209479f;
        shY[b*9+1] = 0.48860251f*uy;
        shY[b*9+2] = 0.48860251f*uz;
        shY[b*9+3] = 0.48860251f*ux;
        shY[b*9+4] = 1.09254843f*ux*uy;
        shY[b*9+5] = 1.09254843f*uy*uz;
        shY[b*9+6] = 0.31539157f*(3.0f*uz*uz - 1.0f);
        shY[b*9+7] = 1.09254843f*ux*uz;
        shY[b*9+8] = 0.54627422f*(ux*ux - uy*uy);
    }
    for (int e = tid; e < NB*9*NC; e += 256) {
        int b = e / (9*NC); int rem = e % (9*NC);
        int xt = rem / NC;  int c = rem % NC;
        int lp = (xt < 1) ? 0 : ((xt < 4) ? 1 : 2);
        int x = xt - LOFF[lp];
        shM[e] = mnl[OFF3[lp] + ((b*NA + i)*(2*lp+1) + x)*NC + c];
    }
    __syncthreads();

    // G[b,z,r=(k*16+c)] per l
    for (int e = tid; e < 1632; e += 256) {
        int l, gb, tpr;
        if (e < 96)       { l = 0; gb = 0;   tpr = 48; }
        else if (e < 672) { l = 1; gb = 96;  tpr = 96; }
        else              { l = 2; gb = 672; tpr = 96; }
        int md = 2*l+1;
        int e2 = e - gb;
        int bz = e2 / tpr, r = e2 % tpr;
        int b = bz / md, z = bz % md;
        int k = r >> 4, c = r & 15;
        int cp = LBASE[l] + k;
        int l1 = CP_L1[cp], l2 = CP_L2[cp];
        int n1 = 2*l1+1, n2 = 2*l2+1;
        const float* cgp = cg + CP_OFF[cp];
        float s = 0.0f;
        for (int x = 0; x < n1; ++x) {
            float mv = shM[(b*9 + LOFF[l1] + x)*NC + c];
            for (int y = 0; y < n2; ++y)
                s += cgp[(x*n2 + y)*md + z] * mv * shY[b*9 + LOFF[l2] + y];
        }
        shG[e] = s;
    }
    __syncthreads();

    // stream wrel, accumulate acc[bz][4 c' columns]; d-sum happens across threads
    float4 accAll[18];
#pragma unroll
    for (int q = 0; q < 18; ++q) accAll[q] = make_float4(0.f, 0.f, 0.f, 0.f);
    const int wave = tid >> 6, lane = tid & 63;
    stream_part<2, 48>(wr0 + (size_t)bx*12288, shG,       accAll,     tid, wave);
    stream_part<6, 96>(wr1 + (size_t)bx*24576, shG + 96,  accAll + 2, tid, wave);
    stream_part<10,96>(wr2 + (size_t)bx*24576, shG + 672, accAll + 8, tid, wave);

    // reduce over lanes sharing the same c'-quad (xor 4,8,16,32), then across waves via LDS
#pragma unroll
    for (int q = 0; q < 18; ++q) {
        float4 v = accAll[q];
#pragma unroll
        for (int m = 4; m <= 32; m <<= 1) {
            v.x += __shfl_xor(v.x, m); v.y += __shfl_xor(v.y, m);
            v.z += __shfl_xor(v.z, m); v.w += __shfl_xor(v.w, m);
        }
        accAll[q] = v;
    }
    if (lane < 4) {
#pragma unroll
        for (int q = 0; q < 18; ++q) shR[(wave*4 + lane)*18 + q] = accAll[q];
    }
    __syncthreads();
    for (int e = tid; e < 288; e += 256) {
        int q = e >> 4, cp = e & 15;
        int qq = cp >> 2, cc = cp & 3;
        float s = 0.0f;
        for (int w = 0; w < 4; ++w) {
            const float* pr = reinterpret_cast<const float*>(&shR[(w*4 + qq)*18 + q]);
            s += pr[cc];
        }
        int l, b, z;
        if (q < 2)      { l = 0; b = q;         z = 0; }
        else if (q < 8) { l = 1; b = (q-2)/3;   z = (q-2)%3; }
        else            { l = 2; b = (q-8)/5;   z = (q-8)%5; }
        atomicAdd(&pout[OFF3[l] + ((b*NA + i)*(2*l+1) + z)*NC + cp], s);
    }
}

// ---------------- K3: scalars epilogue ----------------
__global__ __launch_bounds__(256) void k_scal(const float* __restrict__ pin, float* __restrict__ out)
{
    __shared__ float sp[9*NC];
    const int b = blockIdx.x >> 5, a = blockIdx.x & 31;
    const int tid = threadIdx.x;
    for (int e = tid; e < 9*NC; e += 256) {
        int xt = e / NC, c = e % NC;
        int lp = (xt < 1) ? 0 : ((xt < 4) ? 1 : 2);
        int x = xt - LOFF[lp];
        sp[e] = pin[OFF3[lp] + ((b*NA + a)*(2*lp+1) + x)*NC + c];
    }
    __syncthreads();
    float* orow = out + (size_t)(b*NA + a)*784;
    for (int e = tid; e < 784; e += 256) {
        float v;
        if (e < 16) {
            v = sp[e];
        } else {
            int g = e - 16;
            int lb = g >> 8; int c = (g >> 4) & 15; int d = g & 15;
            int md = 2*lb+1;
            float s = 0.0f;
            for (int z = 0; z < md; ++z)
                s += sp[(LOFF[lb] + z)*NC + c] * sp[(LOFF[lb] + z)*NC + d];
            v = s;
        }
        orow[e] = v;
    }
}

// ---------------- host launch ----------------
extern "C" void kernel_launch(void* const* d_in, const int* in_sizes, int n_in,
                              void* d_out, int out_size, void* d_ws, size_t ws_size,
                              hipStream_t stream)
{
    const float* v0     = (const float*)d_in[0];
    const float* v1     = (const float*)d_in[1];
    const float* v2     = (const float*)d_in[2];
    const float* relpos = (const float*)d_in[3];
    const float* norms  = (const float*)d_in[4];
    const float* wnl[2][3] = {
        {(const float*)d_in[5],  (const float*)d_in[7],  (const float*)d_in[9]},
        {(const float*)d_in[11], (const float*)d_in[13], (const float*)d_in[15]}};
    const float* wrel[2][3] = {
        {(const float*)d_in[6],  (const float*)d_in[8],  (const float*)d_in[10]},
        {(const float*)d_in[12], (const float*)d_in[14], (const float*)d_in[16]}};

    float* ws  = (float*)d_ws;
    float* cg  = ws;                 // 640 floats (615 used)
    float* mnl = ws + 640;           // 9216 floats
    float* pA  = ws + 640 + 9216;    // 9216 floats (layer-0 output parts)
    float* pB  = pA + 9216;          // 9216 floats (layer-1 output parts)
    float* out = (float*)d_out;

    k_cg<<<1, 256, 0, stream>>>(cg);

    for (int L = 0; L < 2; ++L) {
        const float* p0 = L ? pA          : v0;
        const float* p1 = L ? (pA + 1024) : v1;
        const float* p2 = L ? (pA + 4096) : v2;
        float* po = L ? pB : pA;
        hipMemsetAsync(po, 0, 9216*sizeof(float), stream);
        k_nl<0><<<32, 256, 0, stream>>>(p0, p1, p2, norms, wnl[L][0], cg, mnl);
        k_nl<1><<<32, 256, 0, stream>>>(p0, p1, p2, norms, wnl[L][1], cg, mnl);
        k_nl<2><<<32, 256, 0, stream>>>(p0, p1, p2, norms, wnl[L][2], cg, mnl);
        k_rel<<<1024, 256, 0, stream>>>(mnl, relpos, wrel[L][0], wrel[L][1], wrel[L][2], cg, po);
        k_scal<<<64, 256, 0, stream>>>(po, out + (size_t)L * NB * NA * 784);
    }
}

// Round 2
// 818.431 us; speedup vs baseline: 1.1463x; 1.1463x over previous
//
#include <hip/hip_runtime.h>

#define NA 32   // atoms A
#define NB 2    // batch B
#define NC 16   // channels C

// ---- coupling tables (l-grouped, reference loop order) ----
// l=0: (0,0,0),(1,1,0),(2,2,0)
// l=1: (0,1,1),(1,0,1),(1,1,1),(1,2,1),(2,1,1),(2,2,1)
// l=2: (0,2,2),(1,1,2),(1,2,2),(2,0,2),(2,1,2),(2,2,2)
__constant__ int CP_L1[15]   = {0,1,2, 0,1,1,1,2,2, 0,1,1,2,2,2};
__constant__ int CP_L2[15]   = {0,1,2, 1,0,1,2,1,2, 2,1,2,0,1,2};
__constant__ int CP_OFF[15]  = {0,1,10, 35,44,53,80,125,170, 245,270,315,390,415,490};
__constant__ int LBASE[3] = {0,3,9};
__constant__ int LOFF[3]  = {0,1,4};
__constant__ int OFF3[3]  = {0,1024,4096};

// ---------------- compile-time CG table ----------------
constexpr double cfact(int n){ double r=1.0; for(int i=2;i<=n;++i) r*=(double)i; return r; }
constexpr double csqrt(double x){
    double g = (x > 1.0) ? x : 1.0, prev = 0.0;
    for (int i = 0; i < 60 && g != prev; ++i) { prev = g; g = 0.5*(g + x/g); }
    return g;
}
struct CGT { float v[640]; };
constexpr CGT build_cg() {
    CGT t{};
    const int L1[15]={0,1,2,0,1,1,1,2,2,0,1,1,2,2,2};
    const int L2[15]={0,1,2,1,0,1,2,1,2,2,1,2,0,1,2};
    const int LO[15]={0,0,0,1,1,1,1,1,1,2,2,2,2,2,2};
    const int OFF[15]={0,1,10,35,44,53,80,125,170,245,270,315,390,415,490};
    for (int cp=0; cp<15; ++cp){
        int l1=L1[cp], l2=L2[cp], l=LO[cp];
        int n1=2*l1+1, n2=2*l2+1, nl=2*l+1;
        for (int x=0;x<n1;++x) for(int y=0;y<n2;++y) for(int z=0;z<nl;++z){
            int m1=x-l1, m2=y-l2, m=z-l;
            double val=0.0;
            if (m1+m2==m){
                double pre = csqrt((2.0*l+1.0)*cfact(l+l1-l2)*cfact(l-l1+l2)*cfact(l1+l2-l)/cfact(l1+l2+l+1));
                pre *= csqrt(cfact(l+m)*cfact(l-m)*cfact(l1+m1)*cfact(l1-m1)*cfact(l2+m2)*cfact(l2-m2));
                double s=0.0;
                for(int k=0;k<=l1+l2;++k){
                    int d0=k,d1=l1+l2-l-k,d2=l1-m1-k,d3=l2+m2-k,d4=l-l2+m1+k,d5=l-l1-m2+k;
                    if(d0<0||d1<0||d2<0||d3<0||d4<0||d5<0) continue;
                    double term = 1.0/(cfact(d0)*cfact(d1)*cfact(d2)*cfact(d3)*cfact(d4)*cfact(d5));
                    s += (k & 1) ? -term : term;
                }
                val = pre*s;
            }
            t.v[OFF[cp] + (x*n2+y)*nl + z] = (float)val;
        }
    }
    return t;
}
__constant__ CGT CGC = build_cg();

// ---------------- async global->LDS helpers ----------------
__device__ __forceinline__ void async_cp16(const float* g, float* l) {
    __builtin_amdgcn_global_load_lds(
        (const __attribute__((address_space(1))) unsigned int*)g,
        (__attribute__((address_space(3))) unsigned int*)l, 16, 0, 0);
}

// ---------------- K1: message pass + cg_nl + wnl mixing (fused over l) ----------------
template<int L>
__device__ void nl_body(int i,
    const float* __restrict__ p0, const float* __restrict__ p1, const float* __restrict__ p2,
    const float* __restrict__ norms, const float* __restrict__ wnl,
    float* __restrict__ mnl, float* smem)
{
    constexpr int MD  = 2*L+1;
    constexpr int TAU = (L == 0) ? 768 : 1536;
    constexpr int NBZ = NB * MD;

    float* shmp  = smem;                  // 288
    float* shcg  = smem + 288;            // NB*MD*TAU
    float* shred = shcg + NB*MD*TAU;      // 4*16*NBZ

    const int tid = threadIdx.x;

    for (int e = tid; e < NB*9*NC; e += 256) {
        int b = e / (9*NC); int rem = e % (9*NC);
        int xt = rem / NC;  int c = rem % NC;
        int lp = (xt < 1) ? 0 : ((xt < 4) ? 1 : 2);
        int x = xt - LOFF[lp];
        int md = 2*lp+1;
        const float* pp = (lp == 0) ? p0 : ((lp == 1) ? p1 : p2);
        const float* nr = norms + (b*NA + i)*NA;
        float s = 0.0f;
        for (int j = 0; j < NA; ++j) {
            if (nr[j] < 0.5f) s += pp[((b*NA + j)*md + x)*NC + c];
        }
        shmp[e] = s;
    }
    __syncthreads();

    for (int e = tid; e < NB*MD*TAU; e += 256) {
        int t = e % TAU; int rem = e / TAU;
        int z = rem % MD; int b = rem / MD;
        int k = t >> 8; int c = (t >> 4) & 15; int d = t & 15;
        int cp = LBASE[L] + k;
        int l1 = CP_L1[cp], l2 = CP_L2[cp];
        int n1 = 2*l1+1, n2 = 2*l2+1;
        const float* cgp = CGC.v + CP_OFF[cp];
        float s = 0.0f;
        for (int x = 0; x < n1; ++x) {
            float mv = shmp[(b*9 + LOFF[l1] + x)*NC + c];
            for (int y = 0; y < n2; ++y)
                s += cgp[(x*n2 + y)*MD + z] * mv * shmp[(b*9 + LOFF[l2] + y)*NC + d];
        }
        shcg[e] = s;
    }
    __syncthreads();

    const int cidx = tid & 15, tg = tid >> 4;
    float acc[NBZ];
#pragma unroll
    for (int q = 0; q < NBZ; ++q) acc[q] = 0.0f;
    for (int s = 0; s < TAU/16; ++s) {
        int t = tg + (s << 4);
        float wv = wnl[(i*TAU + t)*NC + cidx];
#pragma unroll
        for (int q = 0; q < NBZ; ++q) acc[q] += shcg[q*TAU + t] * wv;
    }
#pragma unroll
    for (int q = 0; q < NBZ; ++q) {
        float v = acc[q];
        v += __shfl_xor(v, 16);
        v += __shfl_xor(v, 32);
        acc[q] = v;
    }
    const int wave = tid >> 6, lane = tid & 63;
    if (lane < 16) {
#pragma unroll
        for (int q = 0; q < NBZ; ++q) shred[(wave*16 + lane)*NBZ + q] = acc[q];
    }
    __syncthreads();
    for (int e = tid; e < 16*NBZ; e += 256) {
        int cc = e & 15, q = e >> 4;
        float s = 0.0f;
        for (int w = 0; w < 4; ++w) s += shred[(w*16 + cc)*NBZ + q];
        int b = q / MD, z = q % MD;
        mnl[OFF3[L] + ((b*NA + i)*MD + z)*NC + cc] = s;
    }
}

__global__ __launch_bounds__(256) void k_nl_all(
    const float* __restrict__ p0, const float* __restrict__ p1, const float* __restrict__ p2,
    const float* __restrict__ norms,
    const float* __restrict__ w0, const float* __restrict__ w1, const float* __restrict__ w2,
    float* __restrict__ mnl, float* __restrict__ po)
{
    __shared__ float smem[16288];
    const int bx = blockIdx.x;
    const int lsel = bx >> 5, i = bx & 31;
    // zero the layer-output accumulator (96 blocks x 96 floats = 9216)
    {
        int base = bx * 96;
        for (int e = threadIdx.x; e < 96; e += 256) po[base + e] = 0.0f;
    }
    if (lsel == 0)      nl_body<0>(i, p0, p1, p2, norms, w0, mnl, smem);
    else if (lsel == 1) nl_body<1>(i, p0, p1, p2, norms, w1, mnl, smem);
    else                nl_body<2>(i, p0, p1, p2, norms, w2, mnl, smem);
}

// ---------------- K2: rel CG product + wrel stream + j-sum ----------------
// slices: s=0 -> l0 (48 rows); s=1,2 -> l1 halves; s=3,4 -> l2 halves.
// block = (slice, i, j-quad); streams 4 x 48KB through per-wave LDS rings.
#define RING_D 8
#define SREL (8192 + 2304 + 72 + 288 + 768)

template<int L>
__device__ void rel_body(int i, int jq, int half,
    const float* __restrict__ wr, const float* __restrict__ mnl,
    const float* __restrict__ relpos, float* __restrict__ pout,
    float* smem)
{
    constexpr int MD  = 2*L+1;
    constexpr int NBZ = 2*MD;
    constexpr int PQ  = (NBZ+3) & ~3;
    constexpr int TAU = (L==0) ? 768 : 1536;
    constexpr int TOTAL = 48;      // 4 jj * 12 chunks

    float*  ring = smem;              // 4 waves * 8 slots * 256 floats
    float*  shG  = smem + 8192;       // 4*48*PQ (PQ<=12 -> 2304)
    float*  shY  = smem + 8192+2304;  // 72
    float*  shM  = shY + 72;          // 288
    float4* shR  = (float4*)(shM + 288); // 16*PQ float4

    const int tid = threadIdx.x;
    const int wave = tid >> 6, lane = tid & 63;

    if (tid < 8) {
        int jj = tid >> 1, b = tid & 1;
        int j = (jq << 2) + jj;
        const float* rp = relpos + (((size_t)(b*NA + i))*NA + j)*3;
        float px = rp[0], py = rp[1], pz = rp[2];
        float rr = sqrtf(px*px + py*py + pz*pz + 1e-6f);
        float ux = px/rr, uy = py/rr, uz = pz/rr;
        float* Y = shY + tid*9;
        Y[0] = 0.28209479f;
        Y[1] = 0.48860251f*uy; Y[2] = 0.48860251f*uz; Y[3] = 0.48860251f*ux;
        Y[4] = 1.09254843f*ux*uy; Y[5] = 1.09254843f*uy*uz;
        Y[6] = 0.31539157f*(3.0f*uz*uz - 1.0f);
        Y[7] = 1.09254843f*ux*uz; Y[8] = 0.54627422f*(ux*ux - uy*uy);
    }
    for (int e = tid; e < NB*9*NC; e += 256) {
        int b = e / (9*NC); int rem = e % (9*NC);
        int xt = rem / NC;  int c = rem % NC;
        int lp = (xt < 1) ? 0 : ((xt < 4) ? 1 : 2);
        shM[e] = mnl[OFF3[lp] + ((b*NA + i)*(2*lp+1) + (xt - LOFF[lp]))*NC + c];
    }
    __syncthreads();

    // G[jj][r][qp], qp-padded to PQ (zeros beyond NBZ)
    for (int e = tid; e < 4*48*PQ; e += 256) {
        int qp = e % PQ; int r = (e/PQ) % 48; int jj = e / (PQ*48);
        float val = 0.0f;
        if (qp < NBZ) {
            int b = qp / MD, z = qp % MD;
            int R = half*48 + r; int k = R >> 4, c = R & 15;
            int cp = LBASE[L] + k;
            int l1 = CP_L1[cp], l2 = CP_L2[cp];
            int n1 = 2*l1+1, n2 = 2*l2+1;
            const float* cgp = CGC.v + CP_OFF[cp];
            float s = 0.0f;
            for (int x = 0; x < n1; ++x) {
                float mv = shM[(b*9 + LOFF[l1] + x)*NC + c];
                for (int y = 0; y < n2; ++y)
                    s += cgp[(x*n2 + y)*MD + z] * mv * shY[((jj<<1)+b)*9 + LOFF[l2] + y];
            }
            val = s;
        }
        shG[e] = val;
    }
    __syncthreads();

    // per-wave ring stream: chunk index c = jj*12 + ch; wave handles r-block `wave`
    const float* wbase = wr + ((size_t)(i*NA + (jq<<2))*TAU + half*(TAU/2))*16;
    float* myring = ring + wave*(RING_D*256);

    float4 acc[PQ];
#pragma unroll
    for (int q = 0; q < PQ; ++q) acc[q] = make_float4(0.f,0.f,0.f,0.f);

    // prologue: issue first RING_D chunks
#pragma unroll
    for (int c = 0; c < RING_D; ++c) {
        int jj = c / 12, ch = c % 12;
        const float* ga = wbase + (size_t)jj*TAU*16 + ch*1024 + wave*256 + lane*4;
        async_cp16(ga, myring + (c & (RING_D-1))*256);
    }

    for (int c = 0; c < TOTAL; ++c) {
        if (c < TOTAL - RING_D)       __builtin_amdgcn_s_waitcnt(0x0F70 | (RING_D-1));
        else if (c == TOTAL - RING_D) __builtin_amdgcn_s_waitcnt(0x0F70);

        int jj = c / 12, ch = c % 12;
        const float4 v = *(const float4*)(myring + (c & (RING_D-1))*256 + lane*4);
        int r = ch*4 + wave;
        const float* gp = shG + (jj*48 + r)*PQ;
#pragma unroll
        for (int q4 = 0; q4 < PQ/4; ++q4) {
            float4 gg = *(const float4*)(gp + q4*4);
            int qb = q4*4;
            acc[qb+0].x += gg.x*v.x; acc[qb+0].y += gg.x*v.y; acc[qb+0].z += gg.x*v.z; acc[qb+0].w += gg.x*v.w;
            acc[qb+1].x += gg.y*v.x; acc[qb+1].y += gg.y*v.y; acc[qb+1].z += gg.y*v.z; acc[qb+1].w += gg.y*v.w;
            acc[qb+2].x += gg.z*v.x; acc[qb+2].y += gg.z*v.y; acc[qb+2].z += gg.z*v.z; acc[qb+2].w += gg.z*v.w;
            acc[qb+3].x += gg.w*v.x; acc[qb+3].y += gg.w*v.y; acc[qb+3].z += gg.w*v.z; acc[qb+3].w += gg.w*v.w;
        }
        // refill the slot we just freed
        if (c + RING_D < TOTAL) {
            int cn = c + RING_D;
            int jn = cn / 12, chn = cn % 12;
            const float* ga = wbase + (size_t)jn*TAU*16 + chn*1024 + wave*256 + lane*4;
            async_cp16(ga, myring + (cn & (RING_D-1))*256);
        }
    }

    // reduce over d (lanes xor 4..32), then across waves via LDS
#pragma unroll
    for (int q = 0; q < PQ; ++q) {
        float4 v = acc[q];
#pragma unroll
        for (int m = 4; m <= 32; m <<= 1) {
            v.x += __shfl_xor(v.x, m); v.y += __shfl_xor(v.y, m);
            v.z += __shfl_xor(v.z, m); v.w += __shfl_xor(v.w, m);
        }
        acc[q] = v;
    }
    if (lane < 4) {
#pragma unroll
        for (int q = 0; q < PQ; ++q) shR[(wave*4 + lane)*PQ + q] = acc[q];
    }
    __syncthreads();
    for (int e = tid; e < NBZ*16; e += 256) {
        int q = e >> 4, cp = e & 15, qq = cp >> 2, cc = cp & 3;
        float s = 0.0f;
        for (int w = 0; w < 4; ++w) {
            const float* pr = (const float*)&shR[(w*4 + qq)*PQ + q];
            s += pr[cc];
        }
        int b = q / MD, z = q % MD;
        atomicAdd(&pout[OFF3[L] + ((b*NA + i)*MD + z)*NC + cp], s);
    }
}

__global__ __launch_bounds__(256) void k_rel(
    const float* __restrict__ mnl, const float* __restrict__ relpos,
    const float* __restrict__ wr0, const float* __restrict__ wr1, const float* __restrict__ wr2,
    float* __restrict__ pout)
{
    __shared__ __align__(16) float smem[SREL];
    const int bx = blockIdx.x;
    const int s = bx >> 8, idx = bx & 255;
    const int i = idx >> 3, jq = idx & 7;
    if (s == 0)      rel_body<0>(i, jq, 0, wr0, mnl, relpos, pout, smem);
    else if (s == 1) rel_body<1>(i, jq, 0, wr1, mnl, relpos, pout, smem);
    else if (s == 2) rel_body<1>(i, jq, 1, wr1, mnl, relpos, pout, smem);
    else if (s == 3) rel_body<2>(i, jq, 0, wr2, mnl, relpos, pout, smem);
    else             rel_body<2>(i, jq, 1, wr2, mnl, relpos, pout, smem);
}

// ---------------- K3: scalars epilogue ----------------
__global__ __launch_bounds__(256) void k_scal(const float* __restrict__ pin, float* __restrict__ out)
{
    __shared__ float sp[9*NC];
    const int b = blockIdx.x >> 5, a = blockIdx.x & 31;
    const int tid = threadIdx.x;
    for (int e = tid; e < 9*NC; e += 256) {
        int xt = e / NC, c = e % NC;
        int lp = (xt < 1) ? 0 : ((xt < 4) ? 1 : 2);
        sp[e] = pin[OFF3[lp] + ((b*NA + a)*(2*lp+1) + (xt - LOFF[lp]))*NC + c];
    }
    __syncthreads();
    float* orow = out + (size_t)(b*NA + a)*784;
    for (int e = tid; e < 784; e += 256) {
        float v;
        if (e < 16) {
            v = sp[e];
        } else {
            int g = e - 16;
            int lb = g >> 8; int c = (g >> 4) & 15; int d = g & 15;
            int md = 2*lb+1;
            float s = 0.0f;
            for (int z = 0; z < md; ++z)
                s += sp[(LOFF[lb] + z)*NC + c] * sp[(LOFF[lb] + z)*NC + d];
            v = s;
        }
        orow[e] = v;
    }
}

// ---------------- host launch ----------------
extern "C" void kernel_launch(void* const* d_in, const int* in_sizes, int n_in,
                              void* d_out, int out_size, void* d_ws, size_t ws_size,
                              hipStream_t stream)
{
    const float* v0     = (const float*)d_in[0];
    const float* v1     = (const float*)d_in[1];
    const float* v2     = (const float*)d_in[2];
    const float* relpos = (const float*)d_in[3];
    const float* norms  = (const float*)d_in[4];
    const float* wnl[2][3] = {
        {(const float*)d_in[5],  (const float*)d_in[7],  (const float*)d_in[9]},
        {(const float*)d_in[11], (const float*)d_in[13], (const float*)d_in[15]}};
    const float* wrel[2][3] = {
        {(const float*)d_in[6],  (const float*)d_in[8],  (const float*)d_in[10]},
        {(const float*)d_in[12], (const float*)d_in[14], (const float*)d_in[16]}};

    float* ws  = (float*)d_ws;
    float* mnl = ws;            // 9216 floats
    float* pA  = ws + 9216;     // 9216 floats
    float* pB  = ws + 18432;    // 9216 floats
    float* out = (float*)d_out;

    for (int L = 0; L < 2; ++L) {
        const float* p0 = L ? pA          : v0;
        const float* p1 = L ? (pA + 1024) : v1;
        const float* p2 = L ? (pA + 4096) : v2;
        float* po = L ? pB : pA;
        k_nl_all<<<96, 256, 0, stream>>>(p0, p1, p2, norms, wnl[L][0], wnl[L][1], wnl[L][2], mnl, po);
        k_rel<<<1280, 256, 0, stream>>>(mnl, relpos, wrel[L][0], wrel[L][1], wrel[L][2], po);
        k_scal<<<64, 256, 0, stream>>>(po, out + (size_t)L * NB * NA * 784);
    }
}

// Round 3
// 541.478 us; speedup vs baseline: 1.7327x; 1.5115x over previous
//
#include <hip/hip_runtime.h>

#define NA 32   // atoms A
#define NB 2    // batch B
#define NC 16   // channels C

// ---- coupling tables (l-grouped, reference loop order) ----
// l=0: (0,0,0),(1,1,0),(2,2,0)
// l=1: (0,1,1),(1,0,1),(1,1,1),(1,2,1),(2,1,1),(2,2,1)
// l=2: (0,2,2),(1,1,2),(1,2,2),(2,0,2),(2,1,2),(2,2,2)
// constexpr versions (compile-time folding when index is constant)
constexpr int KL1[15]   = {0,1,2, 0,1,1,1,2,2, 0,1,1,2,2,2};
constexpr int KL2[15]   = {0,1,2, 1,0,1,2,1,2, 2,1,2,0,1,2};
constexpr int KOFF[15]  = {0,1,10, 35,44,53,80,125,170, 245,270,315,390,415,490};
constexpr int KLBASE[3] = {0,3,9};
constexpr int KLOFF[3]  = {0,1,4};
constexpr int KOFF3[3]  = {0,1024,4096};
// __constant__ mirrors (runtime-indexed paths)
__constant__ int CP_L1[15]   = {0,1,2, 0,1,1,1,2,2, 0,1,1,2,2,2};
__constant__ int CP_L2[15]   = {0,1,2, 1,0,1,2,1,2, 2,1,2,0,1,2};
__constant__ int CP_OFF[15]  = {0,1,10, 35,44,53,80,125,170, 245,270,315,390,415,490};
__constant__ int LBASE[3] = {0,3,9};
__constant__ int LOFF[3]  = {0,1,4};
__constant__ int OFF3[3]  = {0,1024,4096};

// ---------------- compile-time CG table ----------------
constexpr double cfact(int n){ double r=1.0; for(int i=2;i<=n;++i) r*=(double)i; return r; }
constexpr double csqrt(double x){
    double g = (x > 1.0) ? x : 1.0, prev = 0.0;
    for (int i = 0; i < 60 && g != prev; ++i) { prev = g; g = 0.5*(g + x/g); }
    return g;
}
struct CGT { float v[616]; };
constexpr CGT build_cg() {
    CGT t{};
    for (int cp=0; cp<15; ++cp){
        int l1=KL1[cp], l2=KL2[cp];
        int l = (cp<3)?0:((cp<9)?1:2);
        int n1=2*l1+1, n2=2*l2+1, nl=2*l+1;
        for (int x=0;x<n1;++x) for(int y=0;y<n2;++y) for(int z=0;z<nl;++z){
            int m1=x-l1, m2=y-l2, m=z-l;
            double val=0.0;
            if (m1+m2==m){
                double pre = csqrt((2.0*l+1.0)*cfact(l+l1-l2)*cfact(l-l1+l2)*cfact(l1+l2-l)/cfact(l1+l2+l+1));
                pre *= csqrt(cfact(l+m)*cfact(l-m)*cfact(l1+m1)*cfact(l1-m1)*cfact(l2+m2)*cfact(l2-m2));
                double s=0.0;
                for(int k=0;k<=l1+l2;++k){
                    int d0=k,d1=l1+l2-l-k,d2=l1-m1-k,d3=l2+m2-k,d4=l-l2+m1+k,d5=l-l1-m2+k;
                    if(d0<0||d1<0||d2<0||d3<0||d4<0||d5<0) continue;
                    double term = 1.0/(cfact(d0)*cfact(d1)*cfact(d2)*cfact(d3)*cfact(d4)*cfact(d5));
                    s += (k & 1) ? -term : term;
                }
                val = pre*s;
            }
            t.v[KOFF[cp] + (x*n2+y)*nl + z] = (float)val;
        }
    }
    return t;
}
__constant__ CGT CGC = build_cg();

// ---------------- K1: message pass + cg_nl + wnl mixing, one block per (l,b,z,i) ----------------
template<int L>
__device__ void nl_body(int i, int b, int z,
    const float* __restrict__ p0, const float* __restrict__ p1, const float* __restrict__ p2,
    const float* __restrict__ norms, const float* __restrict__ wnl,
    float* __restrict__ mnl, float* smem)
{
    constexpr int MD  = 2*L+1;
    constexpr int TAU = (L == 0) ? 768 : 1536;
    constexpr int NK  = TAU / 256;

    float* shCG = smem;            // 616
    float* mp   = smem + 616;      // 144 (this b only): [xt][c]
    float* shcg = mp + 144;        // TAU
    float* red  = shcg + TAU;      // 64

    const int tid = threadIdx.x;
    const int wave = tid >> 6, lane = tid & 63;

    for (int e = tid; e < 616; e += 256) shCG[e] = CGC.v[e];

    // mp[xt][c] = sum_j conn(b,i,j) * parts[lp][b,j,x,c]
    if (tid < 144) {
        int xt = tid >> 4, c = tid & 15;
        int lp = (xt < 1) ? 0 : ((xt < 4) ? 1 : 2);
        int x = xt - KLOFF[lp];
        int md = 2*lp+1;
        const float* pp = (lp == 0) ? p0 : ((lp == 1) ? p1 : p2);
        const float* nr = norms + (b*NA + i)*NA;
        float s = 0.0f;
        for (int j = 0; j < NA; ++j) {
            if (nr[j] < 0.5f) s += pp[((b*NA + j)*md + x)*NC + c];
        }
        mp[tid] = s;
    }
    __syncthreads();

    // stage b: shcg[t] for t = k*256 + c*16 + d ; this thread: c = tid>>4, d = tid&15
    {
        const int c = tid >> 4, d = tid & 15;
#pragma unroll
        for (int k = 0; k < NK; ++k) {
            const int cp = KLBASE[L] + k;
            const int l1 = KL1[cp], l2 = KL2[cp];
            const int n1 = 2*l1+1, n2 = 2*l2+1;
            float s = 0.0f;
#pragma unroll
            for (int x = 0; x < n1; ++x) {
                float mv = mp[(KLOFF[l1] + x)*NC + c];
#pragma unroll
                for (int y = 0; y < n2; ++y)
                    s += shCG[KOFF[cp] + (x*n2 + y)*MD + z] * mv * mp[(KLOFF[l2] + y)*NC + d];
            }
            shcg[k*256 + tid] = s;
        }
    }
    __syncthreads();

    // stage c: out[c'] = sum_t shcg[t] * wnl[i,t,c']
    {
        const int tg = tid >> 4, cidx = tid & 15;
        float s = 0.0f;
        for (int ss = 0; ss < TAU/16; ++ss) {
            int t = tg + (ss << 4);
            s += shcg[t] * wnl[(i*TAU + t)*NC + cidx];
        }
        s += __shfl_xor(s, 16);
        s += __shfl_xor(s, 32);
        if (lane < 16) red[wave*16 + lane] = s;
    }
    __syncthreads();
    if (tid < 16) {
        float s = red[tid] + red[16 + tid] + red[32 + tid] + red[48 + tid];
        mnl[KOFF3[L] + ((b*NA + i)*MD + z)*NC + tid] = s;
    }
}

// scalars body (used fused and standalone)
__device__ void scal_body(int b, int a, const float* __restrict__ pin,
                          float* __restrict__ out, float* sp)
{
    const int tid = threadIdx.x;
    for (int e = tid; e < 9*NC; e += 256) {
        int xt = e / NC, c = e % NC;
        int lp = (xt < 1) ? 0 : ((xt < 4) ? 1 : 2);
        sp[e] = pin[OFF3[lp] + ((b*NA + a)*(2*lp+1) + (xt - LOFF[lp]))*NC + c];
    }
    __syncthreads();
    float* orow = out + (size_t)(b*NA + a)*784;
    for (int e = tid; e < 784; e += 256) {
        float v;
        if (e < 16) {
            v = sp[e];
        } else {
            int g = e - 16;
            int lb = g >> 8; int c = (g >> 4) & 15; int d = g & 15;
            int md = 2*lb+1;
            float s = 0.0f;
            for (int zz = 0; zz < md; ++zz)
                s += sp[(LOFF[lb] + zz)*NC + c] * sp[(LOFF[lb] + zz)*NC + d];
            v = s;
        }
        orow[e] = v;
    }
}

// grid: 576 nl blocks (+64 scal blocks when prev_po != null, always launched)
__global__ __launch_bounds__(256) void k_nl(
    const float* __restrict__ p0, const float* __restrict__ p1, const float* __restrict__ p2,
    const float* __restrict__ norms,
    const float* __restrict__ w0, const float* __restrict__ w1, const float* __restrict__ w2,
    float* __restrict__ mnl, float* __restrict__ po,
    const float* __restrict__ prev_po, float* __restrict__ prev_out)
{
    __shared__ __align__(16) float smem[2360];
    const int bx = blockIdx.x;
    if (bx >= 576) {
        if (prev_po) {
            int sidx = bx - 576;
            scal_body(sidx >> 5, sidx & 31, prev_po, prev_out, smem);
        }
        return;
    }
    // zero this layer's output accumulator: 576*16 = 9216
    if (threadIdx.x < 16) po[bx*16 + threadIdx.x] = 0.0f;

    const int lq = bx >> 5, i = bx & 31;
    if (lq < 2)      nl_body<0>(i, lq, 0, p0, p1, p2, norms, w0, mnl, smem);
    else if (lq < 8) { int g = lq - 2; nl_body<1>(i, g/3, g%3, p0, p1, p2, norms, w1, mnl, smem); }
    else             { int g = lq - 8; nl_body<2>(i, g/5, g%5, p0, p1, p2, norms, w2, mnl, smem); }
}

// ---------------- K2: rel CG product + wrel stream + j-sum ----------------
// slices: s=0 -> l0 ; s=1,2 -> l1 halves ; s=3,4 -> l2 halves.
// block = (slice, i, j-quad); plain float4 streaming, 48 chunks of 4KB per block.
template<int L>
__device__ void rel_body(int i, int jq, int half,
    const float* __restrict__ wr, const float* __restrict__ mnl,
    const float* __restrict__ relpos, float* __restrict__ pout,
    float* smem)
{
    constexpr int MD  = 2*L+1;
    constexpr int NBZ = 2*MD;
    constexpr int TAU = (L==0) ? 768 : 1536;

    float*  shCG = smem;               // 616
    float*  shY  = smem + 616;         // 72
    float*  shM  = shY + 72;           // 288
    float*  shG  = shM + 288;          // 4*48*NBZ
    float4* shR  = (float4*)(shG + 4*48*NBZ); // 16*NBZ float4

    const int tid = threadIdx.x;
    const int wave = tid >> 6, lane = tid & 63;

    for (int e = tid; e < 616; e += 256) shCG[e] = CGC.v[e];

    if (tid < 8) {
        int jj = tid >> 1, b = tid & 1;
        int j = (jq << 2) + jj;
        const float* rp = relpos + (((size_t)(b*NA + i))*NA + j)*3;
        float px = rp[0], py = rp[1], pz = rp[2];
        float rr = sqrtf(px*px + py*py + pz*pz + 1e-6f);
        float ux = px/rr, uy = py/rr, uz = pz/rr;
        float* Y = shY + tid*9;
        Y[0] = 0.28209479f;
        Y[1] = 0.48860251f*uy; Y[2] = 0.48860251f*uz; Y[3] = 0.48860251f*ux;
        Y[4] = 1.09254843f*ux*uy; Y[5] = 1.09254843f*uy*uz;
        Y[6] = 0.31539157f*(3.0f*uz*uz - 1.0f);
        Y[7] = 1.09254843f*ux*uz; Y[8] = 0.54627422f*(ux*ux - uy*uy);
    }
    for (int e = tid; e < NB*9*NC; e += 256) {
        int b = e / (9*NC); int rem = e % (9*NC);
        int xt = rem / NC;  int c = rem % NC;
        int lp = (xt < 1) ? 0 : ((xt < 4) ? 1 : 2);
        shM[e] = mnl[OFF3[lp] + ((b*NA + i)*(2*lp+1) + (xt - LOFF[lp]))*NC + c];
    }
    __syncthreads();

    // G[jj][r][q] with r = within-half (k,c) row, q = b*MD+z
    for (int e = tid; e < 4*48*NBZ; e += 256) {
        int q = e % NBZ; int r = (e/NBZ) % 48; int jj = e / (NBZ*48);
        int b = q / MD, z = q % MD;
        int R = half*48 + r; int k = R >> 4, c = R & 15;
        int cp = LBASE[L] + k;
        int l1 = CP_L1[cp], l2 = CP_L2[cp];
        int n1 = 2*l1+1, n2 = 2*l2+1;
        const float* cgp = shCG + CP_OFF[cp];
        float s = 0.0f;
        for (int x = 0; x < n1; ++x) {
            float mv = shM[(b*9 + LOFF[l1] + x)*NC + c];
            for (int y = 0; y < n2; ++y)
                s += cgp[(x*n2 + y)*MD + z] * mv * shY[((jj<<1)+b)*9 + LOFF[l2] + y];
        }
        shG[e] = s;
    }
    __syncthreads();

    // stream: thread's float4 at flat f = ch*1024 + tid*4 within a 12288-float (jj,half) slab
    // -> d = (tid>>2)&15, c'quad = tid&3, row r = ch*4 + wave
    const float* wbase = wr + ((size_t)(i*NA + (jq<<2))*TAU + half*(TAU/2))*16;

    float4 acc[NBZ];
#pragma unroll
    for (int q = 0; q < NBZ; ++q) acc[q] = make_float4(0.f,0.f,0.f,0.f);

    for (int jj = 0; jj < 4; ++jj) {
        const float* bb = wbase + (size_t)jj*TAU*16;
        const float* gbase = shG + jj*48*NBZ + wave*NBZ;
#pragma unroll 4
        for (int ch = 0; ch < 12; ++ch) {
            const float4 v = *(const float4*)(bb + ch*1024 + tid*4);
            const float* gp = gbase + ch*4*NBZ;
#pragma unroll
            for (int q = 0; q < NBZ; ++q) {
                float g = gp[q];
                acc[q].x += g*v.x; acc[q].y += g*v.y; acc[q].z += g*v.z; acc[q].w += g*v.w;
            }
        }
    }

    // reduce over d (lanes xor 4..32), then across waves via LDS
#pragma unroll
    for (int q = 0; q < NBZ; ++q) {
        float4 v = acc[q];
#pragma unroll
        for (int m = 4; m <= 32; m <<= 1) {
            v.x += __shfl_xor(v.x, m); v.y += __shfl_xor(v.y, m);
            v.z += __shfl_xor(v.z, m); v.w += __shfl_xor(v.w, m);
        }
        acc[q] = v;
    }
    if (lane < 4) {
#pragma unroll
        for (int q = 0; q < NBZ; ++q) shR[(wave*4 + lane)*NBZ + q] = acc[q];
    }
    __syncthreads();
    for (int e = tid; e < NBZ*16; e += 256) {
        int q = e >> 4, cp = e & 15, qq = cp >> 2, cc = cp & 3;
        float s = 0.0f;
        for (int w = 0; w < 4; ++w) {
            const float* pr = (const float*)&shR[(w*4 + qq)*NBZ + q];
            s += pr[cc];
        }
        int b = q / MD, z = q % MD;
        atomicAdd(&pout[OFF3[L] + ((b*NA + i)*MD + z)*NC + cp], s);
    }
}

__global__ __launch_bounds__(256, 4) void k_rel(
    const float* __restrict__ mnl, const float* __restrict__ relpos,
    const float* __restrict__ wr0, const float* __restrict__ wr1, const float* __restrict__ wr2,
    float* __restrict__ pout)
{
    __shared__ __align__(16) float smem[3536];
    const int bx = blockIdx.x;
    const int s = bx >> 8, idx = bx & 255;
    const int i = idx >> 3, jq = idx & 7;
    if (s == 0)      rel_body<0>(i, jq, 0, wr0, mnl, relpos, pout, smem);
    else if (s == 1) rel_body<1>(i, jq, 0, wr1, mnl, relpos, pout, smem);
    else if (s == 2) rel_body<1>(i, jq, 1, wr1, mnl, relpos, pout, smem);
    else if (s == 3) rel_body<2>(i, jq, 0, wr2, mnl, relpos, pout, smem);
    else             rel_body<2>(i, jq, 1, wr2, mnl, relpos, pout, smem);
}

// ---------------- K3: standalone scalars (last layer) ----------------
__global__ __launch_bounds__(256) void k_scal(const float* __restrict__ pin, float* __restrict__ out)
{
    __shared__ float sp[9*NC];
    scal_body(blockIdx.x >> 5, blockIdx.x & 31, pin, out, sp);
}

// ---------------- host launch ----------------
extern "C" void kernel_launch(void* const* d_in, const int* in_sizes, int n_in,
                              void* d_out, int out_size, void* d_ws, size_t ws_size,
                              hipStream_t stream)
{
    const float* v0     = (const float*)d_in[0];
    const float* v1     = (const float*)d_in[1];
    const float* v2     = (const float*)d_in[2];
    const float* relpos = (const float*)d_in[3];
    const float* norms  = (const float*)d_in[4];
    const float* wnl[2][3] = {
        {(const float*)d_in[5],  (const float*)d_in[7],  (const float*)d_in[9]},
        {(const float*)d_in[11], (const float*)d_in[13], (const float*)d_in[15]}};
    const float* wrel[2][3] = {
        {(const float*)d_in[6],  (const float*)d_in[8],  (const float*)d_in[10]},
        {(const float*)d_in[12], (const float*)d_in[14], (const float*)d_in[16]}};

    float* ws  = (float*)d_ws;
    float* mnl = ws;            // 9216 floats
    float* pA  = ws + 9216;     // 9216 floats (layer-0 parts)
    float* pB  = ws + 18432;    // 9216 floats (layer-1 parts)
    float* out = (float*)d_out;

    // layer 0
    k_nl<<<640, 256, 0, stream>>>(v0, v1, v2, norms,
                                  wnl[0][0], wnl[0][1], wnl[0][2], mnl, pA,
                                  nullptr, nullptr);
    k_rel<<<1280, 256, 0, stream>>>(mnl, relpos, wrel[0][0], wrel[0][1], wrel[0][2], pA);
    // layer 1 (+ fused scalars of layer 0)
    k_nl<<<640, 256, 0, stream>>>(pA, pA + 1024, pA + 4096, norms,
                                  wnl[1][0], wnl[1][1], wnl[1][2], mnl, pB,
                                  pA, out);
    k_rel<<<1280, 256, 0, stream>>>(mnl, relpos, wrel[1][0], wrel[1][1], wrel[1][2], pB);
    k_scal<<<64, 256, 0, stream>>>(pB, out + (size_t)NB * NA * 784);
}

// Round 4
// 496.488 us; speedup vs baseline: 1.8897x; 1.0906x over previous
//
#include <hip/hip_runtime.h>

#define NA 32   // atoms A
#define NB 2    // batch B
#define NC 16   // channels C

// ---- coupling tables (l-grouped, reference loop order) ----
// l=0: (0,0,0),(1,1,0),(2,2,0)
// l=1: (0,1,1),(1,0,1),(1,1,1),(1,2,1),(2,1,1),(2,2,1)
// l=2: (0,2,2),(1,1,2),(1,2,2),(2,0,2),(2,1,2),(2,2,2)
constexpr int KL1[15]   = {0,1,2, 0,1,1,1,2,2, 0,1,1,2,2,2};
constexpr int KL2[15]   = {0,1,2, 1,0,1,2,1,2, 2,1,2,0,1,2};
constexpr int KOFF[15]  = {0,1,10, 35,44,53,80,125,170, 245,270,315,390,415,490};
constexpr int KLBASE[3] = {0,3,9};
constexpr int KLOFF[3]  = {0,1,4};
constexpr int KOFF3[3]  = {0,1024,4096};
__constant__ int CP_L1[15]   = {0,1,2, 0,1,1,1,2,2, 0,1,1,2,2,2};
__constant__ int CP_L2[15]   = {0,1,2, 1,0,1,2,1,2, 2,1,2,0,1,2};
__constant__ int CP_OFF[15]  = {0,1,10, 35,44,53,80,125,170, 245,270,315,390,415,490};
__constant__ int LBASE[3] = {0,3,9};
__constant__ int LOFF[3]  = {0,1,4};
__constant__ int OFF3[3]  = {0,1024,4096};

// ---------------- compile-time CG table ----------------
constexpr double cfact(int n){ double r=1.0; for(int i=2;i<=n;++i) r*=(double)i; return r; }
constexpr double csqrt(double x){
    double g = (x > 1.0) ? x : 1.0, prev = 0.0;
    for (int i = 0; i < 60 && g != prev; ++i) { prev = g; g = 0.5*(g + x/g); }
    return g;
}
struct CGT { float v[616]; };
constexpr CGT build_cg() {
    CGT t{};
    for (int cp=0; cp<15; ++cp){
        int l1=KL1[cp], l2=KL2[cp];
        int l = (cp<3)?0:((cp<9)?1:2);
        int n1=2*l1+1, n2=2*l2+1, nl=2*l+1;
        for (int x=0;x<n1;++x) for(int y=0;y<n2;++y) for(int z=0;z<nl;++z){
            int m1=x-l1, m2=y-l2, m=z-l;
            double val=0.0;
            if (m1+m2==m){
                double pre = csqrt((2.0*l+1.0)*cfact(l+l1-l2)*cfact(l-l1+l2)*cfact(l1+l2-l)/cfact(l1+l2+l+1));
                pre *= csqrt(cfact(l+m)*cfact(l-m)*cfact(l1+m1)*cfact(l1-m1)*cfact(l2+m2)*cfact(l2-m2));
                double s=0.0;
                for(int k=0;k<=l1+l2;++k){
                    int d0=k,d1=l1+l2-l-k,d2=l1-m1-k,d3=l2+m2-k,d4=l-l2+m1+k,d5=l-l1-m2+k;
                    if(d0<0||d1<0||d2<0||d3<0||d4<0||d5<0) continue;
                    double term = 1.0/(cfact(d0)*cfact(d1)*cfact(d2)*cfact(d3)*cfact(d4)*cfact(d5));
                    s += (k & 1) ? -term : term;
                }
                val = pre*s;
            }
            t.v[KOFF[cp] + (x*n2+y)*nl + z] = (float)val;
        }
    }
    return t;
}
__constant__ CGT CGC = build_cg();

// ---------------- K1: message pass + cg_nl + wnl mixing, one block per (l,b,z,i) ----------------
template<int L>
__device__ void nl_body(int i, int b, int z,
    const float* __restrict__ p0, const float* __restrict__ p1, const float* __restrict__ p2,
    const float* __restrict__ norms, const float* __restrict__ wnl,
    float* __restrict__ mnl, float* smem)
{
    constexpr int MD  = 2*L+1;
    constexpr int TAU = (L == 0) ? 768 : 1536;
    constexpr int NK  = TAU / 256;

    float* shCG = smem;            // 616
    float* mp   = smem + 616;      // 144 (this b only): [xt][c]
    float* shcg = mp + 144;        // TAU
    float* red  = shcg + TAU;      // 64 (16 float4)

    const int tid = threadIdx.x;
    const int wave = tid >> 6, lane = tid & 63;

    for (int e = tid; e < 616; e += 256) shCG[e] = CGC.v[e];

    // mp[xt][c] = sum_j conn(b,i,j) * parts[lp][b,j,x,c]   (predicated, unrolled)
    if (tid < 144) {
        int xt = tid >> 4, c = tid & 15;
        int lp = (xt < 1) ? 0 : ((xt < 4) ? 1 : 2);
        int x = xt - KLOFF[lp];
        int md = 2*lp+1;
        const float* pp = (lp == 0) ? p0 : ((lp == 1) ? p1 : p2);
        const float* nr = norms + (b*NA + i)*NA;
        float s = 0.0f;
#pragma unroll
        for (int j = 0; j < NA; ++j) {
            float msk = (nr[j] < 0.5f) ? 1.0f : 0.0f;
            s += msk * pp[((b*NA + j)*md + x)*NC + c];
        }
        mp[tid] = s;
    }
    __syncthreads();

    // stage b: shcg[t], t = k*256 + c*16 + d ; this thread: c = tid>>4, d = tid&15
    {
        const int c = tid >> 4, d = tid & 15;
#pragma unroll
        for (int k = 0; k < NK; ++k) {
            const int cp = KLBASE[L] + k;
            const int l1 = KL1[cp], l2 = KL2[cp];
            const int n1 = 2*l1+1, n2 = 2*l2+1;
            float s = 0.0f;
#pragma unroll
            for (int x = 0; x < n1; ++x) {
                float mv = mp[(KLOFF[l1] + x)*NC + c];
#pragma unroll
                for (int y = 0; y < n2; ++y)
                    s += shCG[KOFF[cp] + (x*n2 + y)*MD + z] * mv * mp[(KLOFF[l2] + y)*NC + d];
            }
            shcg[k*256 + tid] = s;
        }
    }
    __syncthreads();

    // stage c: out[c'] = sum_t shcg[t] * wnl[i,t,c']  — float4 loads, 4-wave t-split
    {
        constexpr int PER = TAU / 4;     // t-range per wave
        constexpr int IT  = PER / 16;
        const int t_low = lane >> 2, c4 = lane & 3;
        const float4* w4 = (const float4*)(wnl + (size_t)i * TAU * 16);
        float4 acc = make_float4(0.f, 0.f, 0.f, 0.f);
        const int tb = wave * PER + t_low;
#pragma unroll 4
        for (int it = 0; it < IT; ++it) {
            int t = tb + it * 16;
            float sc = shcg[t];
            float4 wv = w4[t * 4 + c4];
            acc.x += sc * wv.x; acc.y += sc * wv.y; acc.z += sc * wv.z; acc.w += sc * wv.w;
        }
#pragma unroll
        for (int m = 4; m <= 32; m <<= 1) {
            acc.x += __shfl_xor(acc.x, m); acc.y += __shfl_xor(acc.y, m);
            acc.z += __shfl_xor(acc.z, m); acc.w += __shfl_xor(acc.w, m);
        }
        float4* red4 = (float4*)red;
        if (lane < 4) red4[wave * 4 + lane] = acc;
    }
    __syncthreads();
    if (tid < 16) {
        const float4* red4 = (const float4*)red;
        int c4 = tid >> 2, comp = tid & 3;
        float s = 0.0f;
#pragma unroll
        for (int w = 0; w < 4; ++w) s += ((const float*)&red4[w * 4 + c4])[comp];
        mnl[KOFF3[L] + ((b*NA + i)*MD + z)*NC + tid] = s;
    }
}

// scalars body (used fused and standalone)
__device__ void scal_body(int b, int a, const float* __restrict__ pin,
                          float* __restrict__ out, float* sp)
{
    const int tid = threadIdx.x;
    for (int e = tid; e < 9*NC; e += 256) {
        int xt = e / NC, c = e % NC;
        int lp = (xt < 1) ? 0 : ((xt < 4) ? 1 : 2);
        sp[e] = pin[OFF3[lp] + ((b*NA + a)*(2*lp+1) + (xt - LOFF[lp]))*NC + c];
    }
    __syncthreads();
    float* orow = out + (size_t)(b*NA + a)*784;
    for (int e = tid; e < 784; e += 256) {
        float v;
        if (e < 16) {
            v = sp[e];
        } else {
            int g = e - 16;
            int lb = g >> 8; int c = (g >> 4) & 15; int d = g & 15;
            int md = 2*lb+1;
            float s = 0.0f;
            for (int zz = 0; zz < md; ++zz)
                s += sp[(LOFF[lb] + zz)*NC + c] * sp[(LOFF[lb] + zz)*NC + d];
            v = s;
        }
        orow[e] = v;
    }
}

// grid: 576 nl blocks (+64 scal blocks when prev_po != null, always launched)
__global__ __launch_bounds__(256) void k_nl(
    const float* __restrict__ p0, const float* __restrict__ p1, const float* __restrict__ p2,
    const float* __restrict__ norms,
    const float* __restrict__ w0, const float* __restrict__ w1, const float* __restrict__ w2,
    float* __restrict__ mnl, float* __restrict__ po,
    const float* __restrict__ prev_po, float* __restrict__ prev_out)
{
    __shared__ __align__(16) float smem[2360];
    const int bx = blockIdx.x;
    if (bx >= 576) {
        if (prev_po) {
            int sidx = bx - 576;
            scal_body(sidx >> 5, sidx & 31, prev_po, prev_out, smem);
        }
        return;
    }
    if (threadIdx.x < 16) po[bx*16 + threadIdx.x] = 0.0f;

    const int lq = bx >> 5, i = bx & 31;
    if (lq < 2)      nl_body<0>(i, lq, 0, p0, p1, p2, norms, w0, mnl, smem);
    else if (lq < 8) { int g = lq - 2; nl_body<1>(i, g/3, g%3, p0, p1, p2, norms, w1, mnl, smem); }
    else             { int g = lq - 8; nl_body<2>(i, g/5, g%5, p0, p1, p2, norms, w2, mnl, smem); }
}

// ---------------- K2: rel CG product + wrel stream + j-sum ----------------
// slices: s=0 -> l0 ; s=1,2 -> l1 halves ; s=3,4 -> l2 halves.
// block = (slice, i, j-quad); rotating register pipeline over 48 chunks of 4KB.
template<int L>
__device__ void rel_body(int i, int jq, int half,
    const float* __restrict__ wr, const float* __restrict__ mnl,
    const float* __restrict__ relpos, float* __restrict__ pout,
    float* smem)
{
    constexpr int MD  = 2*L+1;
    constexpr int NBZ = 2*MD;
    constexpr int TAU = (L==0) ? 768 : 1536;
    constexpr int P   = (L==2) ? 5 : 8;   // pipeline depth (VGPR-budgeted)

    float*  shCG = smem;               // 616
    float*  shY  = smem + 616;         // 72
    float*  shM  = shY + 72;           // 288
    float*  shG  = shM + 288;          // 4*48*NBZ
    float4* shR  = (float4*)(shG + 4*48*NBZ); // 16*NBZ float4

    const int tid = threadIdx.x;
    const int wave = tid >> 6, lane = tid & 63;

    for (int e = tid; e < 616; e += 256) shCG[e] = CGC.v[e];

    if (tid < 8) {
        int jj = tid >> 1, b = tid & 1;
        int j = (jq << 2) + jj;
        const float* rp = relpos + (((size_t)(b*NA + i))*NA + j)*3;
        float px = rp[0], py = rp[1], pz = rp[2];
        float rr = sqrtf(px*px + py*py + pz*pz + 1e-6f);
        float ux = px/rr, uy = py/rr, uz = pz/rr;
        float* Y = shY + tid*9;
        Y[0] = 0.28209479f;
        Y[1] = 0.48860251f*uy; Y[2] = 0.48860251f*uz; Y[3] = 0.48860251f*ux;
        Y[4] = 1.09254843f*ux*uy; Y[5] = 1.09254843f*uy*uz;
        Y[6] = 0.31539157f*(3.0f*uz*uz - 1.0f);
        Y[7] = 1.09254843f*ux*uz; Y[8] = 0.54627422f*(ux*ux - uy*uy);
    }
    for (int e = tid; e < NB*9*NC; e += 256) {
        int b = e / (9*NC); int rem = e % (9*NC);
        int xt = rem / NC;  int c = rem % NC;
        int lp = (xt < 1) ? 0 : ((xt < 4) ? 1 : 2);
        shM[e] = mnl[OFF3[lp] + ((b*NA + i)*(2*lp+1) + (xt - LOFF[lp]))*NC + c];
    }
    __syncthreads();

    // G[jj][r][q] with r = within-half (k,c) row, q = b*MD+z
    for (int e = tid; e < 4*48*NBZ; e += 256) {
        int q = e % NBZ; int r = (e/NBZ) % 48; int jj = e / (NBZ*48);
        int b = q / MD, z = q % MD;
        int R = half*48 + r; int k = R >> 4, c = R & 15;
        int cp = LBASE[L] + k;
        int l1 = CP_L1[cp], l2 = CP_L2[cp];
        int n1 = 2*l1+1, n2 = 2*l2+1;
        const float* cgp = shCG + CP_OFF[cp];
        float s = 0.0f;
        for (int x = 0; x < n1; ++x) {
            float mv = shM[(b*9 + LOFF[l1] + x)*NC + c];
            for (int y = 0; y < n2; ++y)
                s += cgp[(x*n2 + y)*MD + z] * mv * shY[((jj<<1)+b)*9 + LOFF[l2] + y];
        }
        shG[e] = s;
    }
    __syncthreads();

    // chunk c -> jj = c/12, ch = c%12; address = wbase + jj*TAU*16 + ch*1024 + tid*4
    const float* wbase = wr + ((size_t)(i*NA + (jq<<2))*TAU + half*(TAU/2))*16;
    const float* tb = wbase + tid*4;

    float4 buf[P];
#pragma unroll
    for (int c = 0; c < P; ++c)
        buf[c] = *(const float4*)(tb + (size_t)(c/12)*TAU*16 + (c%12)*1024);

    float4 acc[NBZ];
#pragma unroll
    for (int q = 0; q < NBZ; ++q) acc[q] = make_float4(0.f,0.f,0.f,0.f);

#pragma unroll
    for (int c = 0; c < 48; ++c) {
        const float4 v = buf[c % P];
        if (c + P < 48)
            buf[c % P] = *(const float4*)(tb + (size_t)((c+P)/12)*TAU*16 + ((c+P)%12)*1024);
        const int jj = c/12, r = (c%12)*4 + wave;
        const float* gp = shG + (jj*48 + r)*NBZ;
        float g[NBZ];
#pragma unroll
        for (int q = 0; q < NBZ; ++q) g[q] = gp[q];
#pragma unroll
        for (int q = 0; q < NBZ; ++q) {
            acc[q].x += g[q]*v.x; acc[q].y += g[q]*v.y;
            acc[q].z += g[q]*v.z; acc[q].w += g[q]*v.w;
        }
    }

    // reduce over d (lanes xor 4..32), then across waves via LDS
#pragma unroll
    for (int q = 0; q < NBZ; ++q) {
        float4 v = acc[q];
#pragma unroll
        for (int m = 4; m <= 32; m <<= 1) {
            v.x += __shfl_xor(v.x, m); v.y += __shfl_xor(v.y, m);
            v.z += __shfl_xor(v.z, m); v.w += __shfl_xor(v.w, m);
        }
        acc[q] = v;
    }
    if (lane < 4) {
#pragma unroll
        for (int q = 0; q < NBZ; ++q) shR[(wave*4 + lane)*NBZ + q] = acc[q];
    }
    __syncthreads();
    for (int e = tid; e < NBZ*16; e += 256) {
        int q = e >> 4, cp = e & 15, qq = cp >> 2, cc = cp & 3;
        float s = 0.0f;
        for (int w = 0; w < 4; ++w) {
            const float* pr = (const float*)&shR[(w*4 + qq)*NBZ + q];
            s += pr[cc];
        }
        int b = q / MD, z = q % MD;
        atomicAdd(&pout[OFF3[L] + ((b*NA + i)*MD + z)*NC + cp], s);
    }
}

__global__ __launch_bounds__(256, 5) void k_rel(
    const float* __restrict__ mnl, const float* __restrict__ relpos,
    const float* __restrict__ wr0, const float* __restrict__ wr1, const float* __restrict__ wr2,
    float* __restrict__ pout)
{
    __shared__ __align__(16) float smem[3536];
    const int bx = blockIdx.x;
    const int s = bx >> 8, idx = bx & 255;
    const int i = idx >> 3, jq = idx & 7;
    if (s == 0)      rel_body<0>(i, jq, 0, wr0, mnl, relpos, pout, smem);
    else if (s == 1) rel_body<1>(i, jq, 0, wr1, mnl, relpos, pout, smem);
    else if (s == 2) rel_body<1>(i, jq, 1, wr1, mnl, relpos, pout, smem);
    else if (s == 3) rel_body<2>(i, jq, 0, wr2, mnl, relpos, pout, smem);
    else             rel_body<2>(i, jq, 1, wr2, mnl, relpos, pout, smem);
}

// ---------------- K3: standalone scalars (last layer) ----------------
__global__ __launch_bounds__(256) void k_scal(const float* __restrict__ pin, float* __restrict__ out)
{
    __shared__ float sp[9*NC];
    scal_body(blockIdx.x >> 5, blockIdx.x & 31, pin, out, sp);
}

// ---------------- host launch ----------------
extern "C" void kernel_launch(void* const* d_in, const int* in_sizes, int n_in,
                              void* d_out, int out_size, void* d_ws, size_t ws_size,
                              hipStream_t stream)
{
    const float* v0     = (const float*)d_in[0];
    const float* v1     = (const float*)d_in[1];
    const float* v2     = (const float*)d_in[2];
    const float* relpos = (const float*)d_in[3];
    const float* norms  = (const float*)d_in[4];
    const float* wnl[2][3] = {
        {(const float*)d_in[5],  (const float*)d_in[7],  (const float*)d_in[9]},
        {(const float*)d_in[11], (const float*)d_in[13], (const float*)d_in[15]}};
    const float* wrel[2][3] = {
        {(const float*)d_in[6],  (const float*)d_in[8],  (const float*)d_in[10]},
        {(const float*)d_in[12], (const float*)d_in[14], (const float*)d_in[16]}};

    float* ws  = (float*)d_ws;
    float* mnl = ws;            // 9216 floats
    float* pA  = ws + 9216;     // 9216 floats (layer-0 parts)
    float* pB  = ws + 18432;    // 9216 floats (layer-1 parts)
    float* out = (float*)d_out;

    // layer 0
    k_nl<<<640, 256, 0, stream>>>(v0, v1, v2, norms,
                                  wnl[0][0], wnl[0][1], wnl[0][2], mnl, pA,
                                  nullptr, nullptr);
    k_rel<<<1280, 256, 0, stream>>>(mnl, relpos, wrel[0][0], wrel[0][1], wrel[0][2], pA);
    // layer 1 (+ fused scalars of layer 0)
    k_nl<<<640, 256, 0, stream>>>(pA, pA + 1024, pA + 4096, norms,
                                  wnl[1][0], wnl[1][1], wnl[1][2], mnl, pB,
                                  pA, out);
    k_rel<<<1280, 256, 0, stream>>>(mnl, relpos, wrel[1][0], wrel[1][1], wrel[1][2], pB);
    k_scal<<<64, 256, 0, stream>>>(pB, out + (size_t)NB * NA * 784);
}